// Round 14
// baseline (174.447 us; speedup 1.0000x reference)
//
#include <hip/hip_runtime.h>
#include <hip/hip_fp16.h>
#include <hip/hip_cooperative_groups.h>
#include <math.h>

namespace cg = cooperative_groups;

#define BB  4096
#define DD  128
#define NCH 16             // j-chunks (256 j each)
#define NP  8              // panels per chunk (32 j each)
#define TB  256            // threads per block (4 waves)
#define CGRID 256          // cooperative grid: 32 ag x 8 (each block: 2 chunks)

typedef __attribute__((ext_vector_type(8))) _Float16 half8;
typedef __attribute__((ext_vector_type(4))) float f32x4;

constexpr float POS_W  = 2.0f;
constexpr float NEG_W  = 40.0f;
constexpr float MARGIN = 0.1f;
constexpr float THRESH = 0.5f;

__device__ __forceinline__ unsigned short f2h(float f) {
  __half h = __float2half(f);
  return __half_as_ushort(h);
}
__device__ __forceinline__ f32x4 mfma16h(half8 a, half8 b, f32x4 c) {
  return __builtin_amdgcn_mfma_f32_16x16x32_f16(a, b, c, 0, 0, 0);
}
__device__ __forceinline__ void gll16(const void* g, void* l) {
  __builtin_amdgcn_global_load_lds(
      (const __attribute__((address_space(1))) void*)g,
      (__attribute__((address_space(3))) void*)l, 16, 0, 0);
}

// LDS panel layout (per array, 32-j panel, 8 KB = 512 slots of 16B):
//   slot = S*128 + H*32 + J  <-> row J, k=[S*32+H*8,+8)
// staging: wave wid covers S=wid; shot s2: dest slots wid*128 + s2*64 + lane
// fragment read (k-step s, j-tile t): slot = s*128 + hi_l*32 + t*16 + l15

// ===================== fused cooperative kernel ============================
__global__ __launch_bounds__(TB, 1) void fused(
    const float* __restrict__ batch, const float* __restrict__ teacher,
    const int* __restrict__ labels, const int* __restrict__ epoch,
    unsigned short* __restrict__ xf, unsigned short* __restrict__ yf,
    float* __restrict__ zsP, float* __restrict__ mpP, float* __restrict__ mnP,
    float* __restrict__ ztP, float* __restrict__ wvP,
    float* __restrict__ psP, float* __restrict__ nsP,
    double* __restrict__ rkP, double* __restrict__ kdP, int* __restrict__ nvP,
    int* __restrict__ cnt, float* __restrict__ out)
{
  __shared__ unsigned short sMem[16384];   // 32 KB panel buffers
  __shared__ int   sJlab[256];
  __shared__ float sRed[256];
  __shared__ double sDr[4], sDk[4];
  __shared__ int    sNn[4];

  cg::grid_group grid = cg::this_grid();

  const int tid  = threadIdx.x;
  const int lane = tid & 63;
  const int wid  = tid >> 6;
  const int bid  = blockIdx.x;

  // ---- Phase 0: fp32 -> fp16 convert (grid-stride, 2 iters) ----
  {
    if (bid == 0 && tid == 0) *cnt = 0;
#pragma unroll
    for (int it = 0; it < 2; ++it) {
      const int i = it * (CGRID * TB) + bid * TB + tid;   // covers 131072
      {
        float4 v = reinterpret_cast<const float4*>(batch)[i];
        ushort4 h;
        h.x = f2h(v.x); h.y = f2h(v.y); h.z = f2h(v.z); h.w = f2h(v.w);
        reinterpret_cast<ushort4*>(xf)[i] = h;
      }
      {
        float4 v = reinterpret_cast<const float4*>(teacher)[i];
        ushort4 h;
        h.x = f2h(v.x); h.y = f2h(v.y); h.z = f2h(v.z); h.w = f2h(v.w);
        reinterpret_cast<ushort4*>(yf)[i] = h;
      }
    }
  }
  grid.sync();

  const int ag   = bid & 31;
  const int ch0  = bid >> 5;          // 0..7; block handles chunks ch0, ch0+8
  const int i0w  = ag * 128 + wid * 32;
  const int l15  = lane & 15;
  const int hi_l = lane >> 4;
  const int rbase = hi_l * 4;
  const int koff  = hi_l * 8;
  const int srow  = lane & 31;
  const int sk0   = wid * 32 + (lane >> 5) * 8;

  int labA[2][4];
#pragma unroll
  for (int at = 0; at < 2; ++at)
#pragma unroll
    for (int r = 0; r < 4; ++r) labA[at][r] = labels[i0w + at * 16 + rbase + r];

  // ---- Phase 1: X+Y Grams -> zs/mp/mn/zt/wv (2 chunks) ----
  {
    half8 Ax[2][4], Ay[2][4];
#pragma unroll
    for (int at = 0; at < 2; ++at) {
      const size_t ab = (size_t)(i0w + at * 16 + l15) * DD + koff;
#pragma unroll
      for (int s = 0; s < 4; ++s) {
        Ax[at][s] = *reinterpret_cast<const half8*>(xf + ab + s * 32);
        Ay[at][s] = *reinterpret_cast<const half8*>(yf + ab + s * 32);
      }
    }

#pragma unroll 1
    for (int cc = ch0; cc < NCH; cc += 8) {
      const int j0ch = cc * 256;
      __syncthreads();               // previous chunk fully done (sJlab/sMem safe)
      sJlab[tid] = labels[j0ch + tid];

      float zs[2][4], mp[2][4], mn[2][4], zt[2][4], wv[2][4];
#pragma unroll
      for (int at = 0; at < 2; ++at)
#pragma unroll
        for (int r = 0; r < 4; ++r) {
          zs[at][r] = 0.f; mp[at][r] = INFINITY; mn[at][r] = -INFINITY;
          zt[at][r] = 0.f; wv[at][r] = 0.f;
        }

      { // prologue stage: panel 0 -> buf 0
        const size_t g0 = (size_t)(j0ch + srow) * DD + sk0;
        gll16(xf + g0,      &sMem[wid * 1024]);
        gll16(xf + g0 + 16, &sMem[wid * 1024 + 512]);
        gll16(yf + g0,      &sMem[4096 + wid * 1024]);
        gll16(yf + g0 + 16, &sMem[4096 + wid * 1024 + 512]);
      }

#pragma unroll 1
      for (int pp = 0; pp < NP; ++pp) {
        const int cur = pp & 1;
        const int cb  = cur * 8192;
        __syncthreads();
        if (pp + 1 < NP) {
          const int nb = (cur ^ 1) * 8192;
          const size_t g0 = (size_t)(j0ch + (pp + 1) * 32 + srow) * DD + sk0;
          gll16(xf + g0,      &sMem[nb + wid * 1024]);
          gll16(xf + g0 + 16, &sMem[nb + wid * 1024 + 512]);
          gll16(yf + g0,      &sMem[nb + 4096 + wid * 1024]);
          gll16(yf + g0 + 16, &sMem[nb + 4096 + wid * 1024 + 512]);
        }

        f32x4 aS[2][2], aT[2][2];
#pragma unroll
        for (int at = 0; at < 2; ++at)
#pragma unroll
          for (int t = 0; t < 2; ++t) { aS[at][t] = {0.f,0.f,0.f,0.f}; aT[at][t] = {0.f,0.f,0.f,0.f}; }
#pragma unroll
        for (int s = 0; s < 4; ++s) {
#pragma unroll
          for (int t = 0; t < 2; ++t) {
            const int ro = (s * 128 + hi_l * 32 + t * 16 + l15) * 8;
            half8 vX = *reinterpret_cast<const half8*>(&sMem[cb + ro]);
            half8 vY = *reinterpret_cast<const half8*>(&sMem[cb + 4096 + ro]);
            aS[0][t] = mfma16h(Ax[0][s], vX, aS[0][t]);
            aS[1][t] = mfma16h(Ax[1][s], vX, aS[1][t]);
            aT[0][t] = mfma16h(Ay[0][s], vY, aT[0][t]);
            aT[1][t] = mfma16h(Ay[1][s], vY, aT[1][t]);
          }
        }

#pragma unroll
        for (int t = 0; t < 2; ++t) {
          const int lj   = sJlab[pp * 32 + t * 16 + l15];
          const int jcol = j0ch + pp * 32 + t * 16 + l15;
#pragma unroll
          for (int at = 0; at < 2; ++at)
#pragma unroll
            for (int r = 0; r < 4; ++r) {
              float sim = aS[at][t][r], tsim = aT[at][t][r];
              bool same = (lj == labA[at][r]);
              float sc = same ? 0.25f : 0.125f;
              float s  = sim * sc;
              float ts = tsim * sc;
              zs[at][r] += __expf(s);
              float et = __expf(ts);
              zt[at][r] += et;
              wv[at][r] += et * (ts - s);
              if (same) {
                if (jcol != i0w + at * 16 + rbase + r) mp[at][r] = fminf(mp[at][r], sim);
              } else {
                mn[at][r] = fmaxf(mn[at][r], sim);
              }
            }
        }
      }

#pragma unroll
      for (int at = 0; at < 2; ++at)
#pragma unroll
        for (int r = 0; r < 4; ++r)
#pragma unroll
          for (int m = 1; m < 16; m <<= 1) {
            zs[at][r] += __shfl_xor(zs[at][r], m);
            mp[at][r] = fminf(mp[at][r], __shfl_xor(mp[at][r], m));
            mn[at][r] = fmaxf(mn[at][r], __shfl_xor(mn[at][r], m));
            zt[at][r] += __shfl_xor(zt[at][r], m);
            wv[at][r] += __shfl_xor(wv[at][r], m);
          }
      if (l15 == 0) {
#pragma unroll
        for (int at = 0; at < 2; ++at)
#pragma unroll
          for (int r = 0; r < 4; ++r) {
            const int i_r = i0w + at * 16 + rbase + r;
            zsP[cc * BB + i_r] = zs[at][r];
            mpP[cc * BB + i_r] = mp[at][r];
            mnP[cc * BB + i_r] = mn[at][r];
            ztP[cc * BB + i_r] = zt[at][r];
            wvP[cc * BB + i_r] = wv[at][r];
          }
      }
    }
  }
  grid.sync();

  // ---- Phase 2: X Gram -> ps/ns (2 chunks) ----
  {
    half8 Ax[2][4];
#pragma unroll
    for (int at = 0; at < 2; ++at) {
      const size_t ab = (size_t)(i0w + at * 16 + l15) * DD + koff;
#pragma unroll
      for (int s = 0; s < 4; ++s)
        Ax[at][s] = *reinterpret_cast<const half8*>(xf + ab + s * 32);
    }

    if (tid < 128) {        // block-wide reduce of the 16 mp/mn chunk partials
      const int aidx = ag * 128 + tid;
      float a = INFINITY, b = -INFINITY;
#pragma unroll
      for (int c = 0; c < NCH; ++c) {
        a = fminf(a, mpP[c * BB + aidx]);
        b = fmaxf(b, mnP[c * BB + aidx]);
      }
      sRed[tid] = a; sRed[128 + tid] = b;
    }
    __syncthreads();
    float mpA[2][4], mnA[2][4];
#pragma unroll
    for (int at = 0; at < 2; ++at)
#pragma unroll
      for (int r = 0; r < 4; ++r) {
        const int al = wid * 32 + at * 16 + rbase + r;
        mpA[at][r] = sRed[al];
        mnA[at][r] = sRed[128 + al];
      }

#pragma unroll 1
    for (int cc = ch0; cc < NCH; cc += 8) {
      const int j0ch = cc * 256;
      __syncthreads();
      sJlab[tid] = labels[j0ch + tid];

      { // prologue stage: panel 0 -> buf 0
        const size_t g0 = (size_t)(j0ch + srow) * DD + sk0;
        gll16(xf + g0,      &sMem[wid * 1024]);
        gll16(xf + g0 + 16, &sMem[wid * 1024 + 512]);
      }

      float ps[2][4], ns[2][4];
#pragma unroll
      for (int at = 0; at < 2; ++at)
#pragma unroll
        for (int r = 0; r < 4; ++r) { ps[at][r] = 0.f; ns[at][r] = 0.f; }

#pragma unroll 1
      for (int pp = 0; pp < NP; ++pp) {
        const int cur = pp & 1;
        const int cb  = cur * 4096;
        __syncthreads();
        if (pp + 1 < NP) {
          const int nb = (cur ^ 1) * 4096;
          const size_t g0 = (size_t)(j0ch + (pp + 1) * 32 + srow) * DD + sk0;
          gll16(xf + g0,      &sMem[nb + wid * 1024]);
          gll16(xf + g0 + 16, &sMem[nb + wid * 1024 + 512]);
        }

        f32x4 acc[2][2];
#pragma unroll
        for (int at = 0; at < 2; ++at)
#pragma unroll
          for (int t = 0; t < 2; ++t) acc[at][t] = {0.f, 0.f, 0.f, 0.f};
#pragma unroll
        for (int s = 0; s < 4; ++s) {
#pragma unroll
          for (int t = 0; t < 2; ++t) {
            const int ro = (s * 128 + hi_l * 32 + t * 16 + l15) * 8;
            half8 vB = *reinterpret_cast<const half8*>(&sMem[cb + ro]);
            acc[0][t] = mfma16h(Ax[0][s], vB, acc[0][t]);
            acc[1][t] = mfma16h(Ax[1][s], vB, acc[1][t]);
          }
        }

#pragma unroll
        for (int t = 0; t < 2; ++t) {
          const int lj   = sJlab[pp * 32 + t * 16 + l15];
          const int jcol = j0ch + pp * 32 + t * 16 + l15;
#pragma unroll
          for (int at = 0; at < 2; ++at)
#pragma unroll
            for (int r = 0; r < 4; ++r) {
              float sim = acc[at][t][r];
              bool same = (lj == labA[at][r]);
              if (same) {
                if (jcol != i0w + at * 16 + rbase + r && (sim - MARGIN < mnA[at][r]))
                  ps[at][r] += __expf(-POS_W * (sim - THRESH));
              } else {
                if (sim + MARGIN > mpA[at][r])
                  ns[at][r] += __expf(NEG_W * (sim - THRESH));
              }
            }
        }
      }

#pragma unroll
      for (int at = 0; at < 2; ++at)
#pragma unroll
        for (int r = 0; r < 4; ++r)
#pragma unroll
          for (int m = 1; m < 16; m <<= 1) {
            ps[at][r] += __shfl_xor(ps[at][r], m);
            ns[at][r] += __shfl_xor(ns[at][r], m);
          }
      if (l15 == 0) {
#pragma unroll
        for (int at = 0; at < 2; ++at)
#pragma unroll
          for (int r = 0; r < 4; ++r) {
            const int i_r = i0w + at * 16 + rbase + r;
            psP[cc * BB + i_r] = ps[at][r];
            nsP[cc * BB + i_r] = ns[at][r];
          }
      }
    }
  }
  grid.sync();

  // ---- Phase 3: finalize (blocks 0..15) ----
  if (bid < 16) {
    const int i = bid * TB + tid;

    float zs = 0.f, zt = 0.f, wv = 0.f, ps = 0.f, ns = 0.f;
#pragma unroll
    for (int c = 0; c < NCH; ++c) {
      zs += zsP[c * BB + i];
      zt += ztP[c * BB + i];
      wv += wvP[c * BB + i];
      ps += psP[c * BB + i];
      ns += nsP[c * BB + i];
    }
    double kd = (double)(wv / zt + __logf(zs) - __logf(zt));
    double rank = 0.0; int nv = 0;
    if (ps > 0.f && ns > 0.f) {
      rank = (double)(log1pf(ps) * 0.5f + log1pf(ns) * 0.025f);
      nv = 1;
    }
#pragma unroll
    for (int o = 32; o; o >>= 1) {
      rank += __shfl_xor(rank, o);
      kd   += __shfl_xor(kd, o);
      nv   += __shfl_xor(nv, o);
    }
    if (lane == 0) { sDr[wid] = rank; sDk[wid] = kd; sNn[wid] = nv; }
    __syncthreads();
    if (tid == 0) {
      double R_ = 0.0, K_ = 0.0; int N_ = 0;
      for (int w2 = 0; w2 < 4; ++w2) { R_ += sDr[w2]; K_ += sDk[w2]; N_ += sNn[w2]; }
      rkP[bid] = R_;
      kdP[bid] = K_;
      nvP[bid] = N_;
      __threadfence();
      int old = atomicAdd(cnt, 1);
      if (old == 15) {
        __threadfence();
        double RT = 0.0, KT = 0.0; int NT = 0;
        for (int b = 0; b < 16; ++b) { RT += rkP[b]; KT += kdP[b]; NT += nvP[b]; }
        double loss_rank = RT / (double)(NT < 1 ? 1 : NT);
        double loss_kd   = KT / (double)BB;
        double wgt = (double)epoch[0] * 0.16;
        out[0] = (float)(loss_rank + wgt * loss_kd);
        out[1] = (float)loss_rank;
        out[2] = (float)loss_kd;
        *cnt = 0;
      }
    }
  }
}

// ===================== fallback: round-12 4-kernel pipeline ================
__global__ __launch_bounds__(256) void k0(
    const float* __restrict__ b, const float* __restrict__ t,
    unsigned short* __restrict__ xf, unsigned short* __restrict__ yf,
    int* __restrict__ cnt)
{
  const int i = blockIdx.x * 256 + threadIdx.x;
  if (i == 0) *cnt = 0;
  {
    float4 v = reinterpret_cast<const float4*>(b)[i];
    ushort4 h;
    h.x = f2h(v.x); h.y = f2h(v.y); h.z = f2h(v.z); h.w = f2h(v.w);
    reinterpret_cast<ushort4*>(xf)[i] = h;
  }
  {
    float4 v = reinterpret_cast<const float4*>(t)[i];
    ushort4 h;
    h.x = f2h(v.x); h.y = f2h(v.y); h.z = f2h(v.z); h.w = f2h(v.w);
    reinterpret_cast<ushort4*>(yf)[i] = h;
  }
}

__global__ __launch_bounds__(TB, 2) void kG1(
    const unsigned short* __restrict__ xf, const unsigned short* __restrict__ yf,
    const int* __restrict__ labels,
    float* __restrict__ zsP, float* __restrict__ mpP, float* __restrict__ mnP,
    float* __restrict__ ztP, float* __restrict__ wvP)
{
  __shared__ unsigned short sB[2][8192];
  __shared__ int sJlab[256];

  const int tid  = threadIdx.x;
  const int lane = tid & 63;
  const int wid  = tid >> 6;
  const int ag   = blockIdx.x & 31;
  const int ch   = blockIdx.x >> 5;
  const int i0w  = ag * 128 + wid * 32;
  const int l15  = lane & 15;
  const int hi_l = lane >> 4;
  const int rbase = hi_l * 4;
  const int koff  = hi_l * 8;
  const int j0ch  = ch * 256;
  const int srow  = lane & 31;
  const int sk0   = wid * 32 + (lane >> 5) * 8;

  sJlab[tid] = labels[j0ch + tid];

  half8 Ax[2][4], Ay[2][4];
#pragma unroll
  for (int at = 0; at < 2; ++at) {
    const size_t ab = (size_t)(i0w + at * 16 + l15) * DD + koff;
#pragma unroll
    for (int s = 0; s < 4; ++s) {
      Ax[at][s] = *reinterpret_cast<const half8*>(xf + ab + s * 32);
      Ay[at][s] = *reinterpret_cast<const half8*>(yf + ab + s * 32);
    }
  }
  int labA[2][4];
#pragma unroll
  for (int at = 0; at < 2; ++at)
#pragma unroll
    for (int r = 0; r < 4; ++r) labA[at][r] = labels[i0w + at * 16 + rbase + r];

  float zs[2][4], mp[2][4], mn[2][4], zt[2][4], wv[2][4];
#pragma unroll
  for (int at = 0; at < 2; ++at)
#pragma unroll
    for (int r = 0; r < 4; ++r) {
      zs[at][r] = 0.f; mp[at][r] = INFINITY; mn[at][r] = -INFINITY;
      zt[at][r] = 0.f; wv[at][r] = 0.f;
    }

  {
    const size_t g0 = (size_t)(j0ch + srow) * DD + sk0;
    gll16(xf + g0,      &sB[0][wid * 1024]);
    gll16(xf + g0 + 16, &sB[0][wid * 1024 + 512]);
    gll16(yf + g0,      &sB[0][4096 + wid * 1024]);
    gll16(yf + g0 + 16, &sB[0][4096 + wid * 1024 + 512]);
  }

#pragma unroll 1
  for (int pp = 0; pp < NP; ++pp) {
    const int cur = pp & 1;
    __syncthreads();
    if (pp + 1 < NP) {
      const size_t g0 = (size_t)(j0ch + (pp + 1) * 32 + srow) * DD + sk0;
      gll16(xf + g0,      &sB[cur ^ 1][wid * 1024]);
      gll16(xf + g0 + 16, &sB[cur ^ 1][wid * 1024 + 512]);
      gll16(yf + g0,      &sB[cur ^ 1][4096 + wid * 1024]);
      gll16(yf + g0 + 16, &sB[cur ^ 1][4096 + wid * 1024 + 512]);
    }

    f32x4 aS[2][2], aT[2][2];
#pragma unroll
    for (int at = 0; at < 2; ++at)
#pragma unroll
      for (int t = 0; t < 2; ++t) { aS[at][t] = {0.f,0.f,0.f,0.f}; aT[at][t] = {0.f,0.f,0.f,0.f}; }
#pragma unroll
    for (int s = 0; s < 4; ++s) {
#pragma unroll
      for (int t = 0; t < 2; ++t) {
        const int ro = (s * 128 + hi_l * 32 + t * 16 + l15) * 8;
        half8 vX = *reinterpret_cast<const half8*>(&sB[cur][ro]);
        half8 vY = *reinterpret_cast<const half8*>(&sB[cur][4096 + ro]);
        aS[0][t] = mfma16h(Ax[0][s], vX, aS[0][t]);
        aS[1][t] = mfma16h(Ax[1][s], vX, aS[1][t]);
        aT[0][t] = mfma16h(Ay[0][s], vY, aT[0][t]);
        aT[1][t] = mfma16h(Ay[1][s], vY, aT[1][t]);
      }
    }

#pragma unroll
    for (int t = 0; t < 2; ++t) {
      const int lj   = sJlab[pp * 32 + t * 16 + l15];
      const int jcol = j0ch + pp * 32 + t * 16 + l15;
#pragma unroll
      for (int at = 0; at < 2; ++at)
#pragma unroll
        for (int r = 0; r < 4; ++r) {
          float sim = aS[at][t][r], tsim = aT[at][t][r];
          bool same = (lj == labA[at][r]);
          float sc = same ? 0.25f : 0.125f;
          float s  = sim * sc;
          float ts = tsim * sc;
          zs[at][r] += __expf(s);
          float et = __expf(ts);
          zt[at][r] += et;
          wv[at][r] += et * (ts - s);
          if (same) {
            if (jcol != i0w + at * 16 + rbase + r) mp[at][r] = fminf(mp[at][r], sim);
          } else {
            mn[at][r] = fmaxf(mn[at][r], sim);
          }
        }
    }
  }

#pragma unroll
  for (int at = 0; at < 2; ++at)
#pragma unroll
    for (int r = 0; r < 4; ++r)
#pragma unroll
      for (int m = 1; m < 16; m <<= 1) {
        zs[at][r] += __shfl_xor(zs[at][r], m);
        mp[at][r] = fminf(mp[at][r], __shfl_xor(mp[at][r], m));
        mn[at][r] = fmaxf(mn[at][r], __shfl_xor(mn[at][r], m));
        zt[at][r] += __shfl_xor(zt[at][r], m);
        wv[at][r] += __shfl_xor(wv[at][r], m);
      }
  if (l15 == 0) {
#pragma unroll
    for (int at = 0; at < 2; ++at)
#pragma unroll
      for (int r = 0; r < 4; ++r) {
        const int i_r = i0w + at * 16 + rbase + r;
        zsP[ch * BB + i_r] = zs[at][r];
        mpP[ch * BB + i_r] = mp[at][r];
        mnP[ch * BB + i_r] = mn[at][r];
        ztP[ch * BB + i_r] = zt[at][r];
        wvP[ch * BB + i_r] = wv[at][r];
      }
  }
}

__global__ __launch_bounds__(TB, 3) void kG2(
    const unsigned short* __restrict__ xf,
    const int* __restrict__ labels,
    const float* __restrict__ mpP, const float* __restrict__ mnP,
    float* __restrict__ psP, float* __restrict__ nsP)
{
  __shared__ unsigned short sX[2][4096];
  __shared__ int sJlab[256];
  __shared__ float sMPr[128], sMNr[128];

  const int tid  = threadIdx.x;
  const int lane = tid & 63;
  const int wid  = tid >> 6;
  const int ag   = blockIdx.x & 31;
  const int ch   = blockIdx.x >> 5;
  const int i0w  = ag * 128 + wid * 32;
  const int l15  = lane & 15;
  const int hi_l = lane >> 4;
  const int rbase = hi_l * 4;
  const int koff  = hi_l * 8;
  const int j0ch  = ch * 256;
  const int srow  = lane & 31;
  const int sk0   = wid * 32 + (lane >> 5) * 8;

  {
    const size_t g0 = (size_t)(j0ch + srow) * DD + sk0;
    gll16(xf + g0,      &sX[0][wid * 1024]);
    gll16(xf + g0 + 16, &sX[0][wid * 1024 + 512]);
  }

  sJlab[tid] = labels[j0ch + tid];
  if (tid < 128) {
    const int aidx = ag * 128 + tid;
    float a = INFINITY, b = -INFINITY;
#pragma unroll
    for (int c = 0; c < NCH; ++c) {
      a = fminf(a, mpP[c * BB + aidx]);
      b = fmaxf(b, mnP[c * BB + aidx]);
    }
    sMPr[tid] = a; sMNr[tid] = b;
  }

  half8 Ax[2][4];
#pragma unroll
  for (int at = 0; at < 2; ++at) {
    const size_t ab = (size_t)(i0w + at * 16 + l15) * DD + koff;
#pragma unroll
    for (int s = 0; s < 4; ++s)
      Ax[at][s] = *reinterpret_cast<const half8*>(xf + ab + s * 32);
  }
  int labA[2][4];
#pragma unroll
  for (int at = 0; at < 2; ++at)
#pragma unroll
    for (int r = 0; r < 4; ++r) labA[at][r] = labels[i0w + at * 16 + rbase + r];

  __syncthreads();
  float mpA[2][4], mnA[2][4];
#pragma unroll
  for (int at = 0; at < 2; ++at)
#pragma unroll
    for (int r = 0; r < 4; ++r) {
      const int al = wid * 32 + at * 16 + rbase + r;
      mpA[at][r] = sMPr[al];
      mnA[at][r] = sMNr[al];
    }

  float ps[2][4], ns[2][4];
#pragma unroll
  for (int at = 0; at < 2; ++at)
#pragma unroll
    for (int r = 0; r < 4; ++r) { ps[at][r] = 0.f; ns[at][r] = 0.f; }

#pragma unroll 1
  for (int pp = 0; pp < NP; ++pp) {
    const int cur = pp & 1;
    if (pp) __syncthreads();
    if (pp + 1 < NP) {
      const size_t g0 = (size_t)(j0ch + (pp + 1) * 32 + srow) * DD + sk0;
      gll16(xf + g0,      &sX[cur ^ 1][wid * 1024]);
      gll16(xf + g0 + 16, &sX[cur ^ 1][wid * 1024 + 512]);
    }

    f32x4 acc[2][2];
#pragma unroll
    for (int at = 0; at < 2; ++at)
#pragma unroll
      for (int t = 0; t < 2; ++t) acc[at][t] = {0.f, 0.f, 0.f, 0.f};
#pragma unroll
    for (int s = 0; s < 4; ++s) {
#pragma unroll
      for (int t = 0; t < 2; ++t) {
        const int ro = (s * 128 + hi_l * 32 + t * 16 + l15) * 8;
        half8 vB = *reinterpret_cast<const half8*>(&sX[cur][ro]);
        acc[0][t] = mfma16h(Ax[0][s], vB, acc[0][t]);
        acc[1][t] = mfma16h(Ax[1][s], vB, acc[1][t]);
      }
    }

#pragma unroll
    for (int t = 0; t < 2; ++t) {
      const int lj   = sJlab[pp * 32 + t * 16 + l15];
      const int jcol = j0ch + pp * 32 + t * 16 + l15;
#pragma unroll
      for (int at = 0; at < 2; ++at)
#pragma unroll
        for (int r = 0; r < 4; ++r) {
          float sim = acc[at][t][r];
          bool same = (lj == labA[at][r]);
          if (same) {
            if (jcol != i0w + at * 16 + rbase + r && (sim - MARGIN < mnA[at][r]))
              ps[at][r] += __expf(-POS_W * (sim - THRESH));
          } else {
            if (sim + MARGIN > mpA[at][r])
              ns[at][r] += __expf(NEG_W * (sim - THRESH));
          }
        }
    }
  }

#pragma unroll
  for (int at = 0; at < 2; ++at)
#pragma unroll
    for (int r = 0; r < 4; ++r)
#pragma unroll
      for (int m = 1; m < 16; m <<= 1) {
        ps[at][r] += __shfl_xor(ps[at][r], m);
        ns[at][r] += __shfl_xor(ns[at][r], m);
      }
  if (l15 == 0) {
#pragma unroll
    for (int at = 0; at < 2; ++at)
#pragma unroll
      for (int r = 0; r < 4; ++r) {
        const int i_r = i0w + at * 16 + rbase + r;
        psP[ch * BB + i_r] = ps[at][r];
        nsP[ch * BB + i_r] = ns[at][r];
      }
  }
}

__global__ __launch_bounds__(512) void kD(
    const float* __restrict__ zsP, const float* __restrict__ ztP,
    const float* __restrict__ wvP, const float* __restrict__ psP,
    const float* __restrict__ nsP, const int* __restrict__ epoch,
    double* __restrict__ rkP, double* __restrict__ kdP, int* __restrict__ nvP,
    int* __restrict__ cnt, float* __restrict__ out)
{
  __shared__ double sR[8], sK[8];
  __shared__ int    sN[8];
  const int tid = threadIdx.x;
  const int lane = tid & 63;
  const int wid = tid >> 6;
  const int i = blockIdx.x * 512 + tid;

  float zs = 0.f, zt = 0.f, wv = 0.f, ps = 0.f, ns = 0.f;
#pragma unroll
  for (int c = 0; c < NCH; ++c) {
    zs += zsP[c * BB + i];
    zt += ztP[c * BB + i];
    wv += wvP[c * BB + i];
    ps += psP[c * BB + i];
    ns += nsP[c * BB + i];
  }
  double kd = (double)(wv / zt + __logf(zs) - __logf(zt));
  double rank = 0.0; int nv = 0;
  if (ps > 0.f && ns > 0.f) {
    rank = (double)(log1pf(ps) * 0.5f + log1pf(ns) * 0.025f);
    nv = 1;
  }
#pragma unroll
  for (int o = 32; o; o >>= 1) {
    rank += __shfl_xor(rank, o);
    kd   += __shfl_xor(kd, o);
    nv   += __shfl_xor(nv, o);
  }
  if (lane == 0) { sR[wid] = rank; sK[wid] = kd; sN[wid] = nv; }
  __syncthreads();
  if (tid == 0) {
    double R_ = 0.0, K_ = 0.0; int N_ = 0;
    for (int w = 0; w < 8; ++w) { R_ += sR[w]; K_ += sK[w]; N_ += sN[w]; }
    rkP[blockIdx.x] = R_;
    kdP[blockIdx.x] = K_;
    nvP[blockIdx.x] = N_;
    __threadfence();
    int old = atomicAdd(cnt, 1);
    if (old == 7) {
      __threadfence();
      double RT = 0.0, KT = 0.0; int NT = 0;
      for (int b = 0; b < 8; ++b) { RT += rkP[b]; KT += kdP[b]; NT += nvP[b]; }
      double loss_rank = RT / (double)(NT < 1 ? 1 : NT);
      double loss_kd   = KT / (double)BB;
      double wgt = (double)epoch[0] * 0.16;
      out[0] = (float)(loss_rank + wgt * loss_kd);
      out[1] = (float)loss_rank;
      out[2] = (float)loss_kd;
      *cnt = 0;
    }
  }
}

extern "C" void kernel_launch(void* const* d_in, const int* in_sizes, int n_in,
                              void* d_out, int out_size, void* d_ws, size_t ws_size,
                              hipStream_t stream)
{
  (void)in_sizes; (void)n_in; (void)out_size; (void)ws_size;
  const float* batch   = (const float*)d_in[0];
  const float* teacher = (const float*)d_in[1];
  const int*   labels  = (const int*)d_in[2];
  const int*   epoch   = (const int*)d_in[3];
  float* out = (float*)d_out;

  char* w = (char*)d_ws;
  const size_t MB = 1048576;
  unsigned short* xf = (unsigned short*)(w + 0 * MB);
  unsigned short* yf = (unsigned short*)(w + 1 * MB);
  const size_t PCH = (size_t)NCH * BB * sizeof(float);
  float* zsP = (float*)(w + 2 * MB + 0 * PCH);
  float* mpP = (float*)(w + 2 * MB + 1 * PCH);
  float* mnP = (float*)(w + 2 * MB + 2 * PCH);
  float* ztP = (float*)(w + 2 * MB + 3 * PCH);
  float* wvP = (float*)(w + 2 * MB + 4 * PCH);
  float* psP = (float*)(w + 2 * MB + 5 * PCH);
  float* nsP = (float*)(w + 2 * MB + 6 * PCH);
  double* rkP = (double*)(w + 4 * MB);
  double* kdP = (double*)(w + 4 * MB + 256);
  int*    nvP = (int*)(w + 4 * MB + 512);
  int*    cnt = (int*)(w + 4 * MB + 640);

  void* args[] = { (void*)&batch, (void*)&teacher, (void*)&labels, (void*)&epoch,
                   (void*)&xf, (void*)&yf,
                   (void*)&zsP, (void*)&mpP, (void*)&mnP, (void*)&ztP, (void*)&wvP,
                   (void*)&psP, (void*)&nsP,
                   (void*)&rkP, (void*)&kdP, (void*)&nvP, (void*)&cnt, (void*)&out };
  hipError_t err = hipLaunchCooperativeKernel((const void*)fused, dim3(CGRID),
                                              dim3(TB), args, 0, stream);
  if (err != hipSuccess) {
    // deterministic fallback: proven 4-kernel pipeline (round 12)
    k0<<<dim3(BB * DD / 4 / 256), dim3(256), 0, stream>>>(batch, teacher, xf, yf, cnt);
    kG1<<<dim3(32 * NCH), dim3(TB), 0, stream>>>(xf, yf, labels,
                                                 zsP, mpP, mnP, ztP, wvP);
    kG2<<<dim3(32 * NCH), dim3(TB), 0, stream>>>(xf, labels, mpP, mnP, psP, nsP);
    kD<<<dim3(8), dim3(512), 0, stream>>>(zsP, ztP, wvP, psP, nsP, epoch,
                                          rkP, kdP, nvP, cnt, out);
  }
}

// Round 15
// 69.503 us; speedup vs baseline: 2.5099x; 2.5099x over previous
//
#include <hip/hip_runtime.h>
#include <hip/hip_fp16.h>
#include <math.h>

#define BB  4096
#define DD  128
#define NCH 32             // j-chunks (128 j each)
#define NP  4              // panels per chunk (32 j each)
#define TB  256            // threads per block (4 waves)

typedef __attribute__((ext_vector_type(8))) _Float16 half8;
typedef __attribute__((ext_vector_type(4))) float f32x4;

constexpr float POS_W  = 2.0f;
constexpr float NEG_W  = 40.0f;
constexpr float MARGIN = 0.1f;
constexpr float THRESH = 0.5f;

__device__ __forceinline__ unsigned short f2h(float f) {
  __half h = __float2half(f);
  return __half_as_ushort(h);
}
__device__ __forceinline__ f32x4 mfma16h(half8 a, half8 b, f32x4 c) {
  return __builtin_amdgcn_mfma_f32_16x16x32_f16(a, b, c, 0, 0, 0);
}
// async global->LDS, 16B per lane; lds dest = uniform base + lane*16
__device__ __forceinline__ void gll16(const void* g, void* l) {
  __builtin_amdgcn_global_load_lds(
      (const __attribute__((address_space(1))) void*)g,
      (__attribute__((address_space(3))) void*)l, 16, 0, 0);
}

// ============ k0: fp32 -> fp16 for batch & teacher (+ zero cnt) ============
__global__ __launch_bounds__(256) void k0(
    const float* __restrict__ b, const float* __restrict__ t,
    unsigned short* __restrict__ xf, unsigned short* __restrict__ yf,
    int* __restrict__ cnt)
{
  const int i = blockIdx.x * 256 + threadIdx.x;   // < BB*DD/4 = 131072
  if (i == 0) *cnt = 0;
  {
    float4 v = reinterpret_cast<const float4*>(b)[i];
    ushort4 h;
    h.x = f2h(v.x); h.y = f2h(v.y); h.z = f2h(v.z); h.w = f2h(v.w);
    reinterpret_cast<ushort4*>(xf)[i] = h;
  }
  {
    float4 v = reinterpret_cast<const float4*>(t)[i];
    ushort4 h;
    h.x = f2h(v.x); h.y = f2h(v.y); h.z = f2h(v.z); h.w = f2h(v.w);
    reinterpret_cast<ushort4*>(yf)[i] = h;
  }
}

// LDS panel layout (per array, 32-j panel, 8 KB = 512 slots of 16B):
//   slot = S*128 + H*32 + J  <-> row J, k=[S*32+H*8,+8)
// staging: wave wid covers S=wid; shot s2: dest slots wid*128 + s2*64 + lane
//   source row = j0p + (lane&31), k = wid*32 + (s2*2 + (lane>>5))*8
// fragment read (k-step s, j-tile t): slot = s*128 + hi_l*32 + t*16 + l15

// ============ kG1: batch+teacher Grams -> zs/mp/mn/zt/wv chunk partials ====
// grid = 32 anchor-groups x 32 chunks = 1024 blocks (4 blocks/CU)
__global__ __launch_bounds__(TB, 2) void kG1(
    const unsigned short* __restrict__ xf, const unsigned short* __restrict__ yf,
    const int* __restrict__ labels,
    float* __restrict__ zsP, float* __restrict__ mpP, float* __restrict__ mnP,
    float* __restrict__ ztP, float* __restrict__ wvP)
{
  __shared__ unsigned short sB[2][8192];   // 2 bufs x (X 8KB + Y 8KB) = 32 KB
  __shared__ int sJlab[128];

  const int tid  = threadIdx.x;
  const int lane = tid & 63;
  const int wid  = tid >> 6;
  const int ag   = blockIdx.x & 31;
  const int ch   = blockIdx.x >> 5;        // 0..31
  const int i0w  = ag * 128 + wid * 32;
  const int l15  = lane & 15;
  const int hi_l = lane >> 4;
  const int rbase = hi_l * 4;
  const int koff  = hi_l * 8;
  const int j0ch  = ch * 128;
  const int srow  = lane & 31;
  const int sk0   = wid * 32 + (lane >> 5) * 8;

  if (tid < 128) sJlab[tid] = labels[j0ch + tid];

  half8 Ax[2][4], Ay[2][4];
#pragma unroll
  for (int at = 0; at < 2; ++at) {
    const size_t ab = (size_t)(i0w + at * 16 + l15) * DD + koff;
#pragma unroll
    for (int s = 0; s < 4; ++s) {
      Ax[at][s] = *reinterpret_cast<const half8*>(xf + ab + s * 32);
      Ay[at][s] = *reinterpret_cast<const half8*>(yf + ab + s * 32);
    }
  }
  int labA[2][4];
#pragma unroll
  for (int at = 0; at < 2; ++at)
#pragma unroll
    for (int r = 0; r < 4; ++r) labA[at][r] = labels[i0w + at * 16 + rbase + r];

  float zs[2][4], mp[2][4], mn[2][4], zt[2][4], wv[2][4];
#pragma unroll
  for (int at = 0; at < 2; ++at)
#pragma unroll
    for (int r = 0; r < 4; ++r) {
      zs[at][r] = 0.f; mp[at][r] = INFINITY; mn[at][r] = -INFINITY;
      zt[at][r] = 0.f; wv[at][r] = 0.f;
    }

  { // prologue stage: panel 0 -> buf 0 (X then Y, 2 shots each)
    const size_t g0 = (size_t)(j0ch + srow) * DD + sk0;
    gll16(xf + g0,      &sB[0][wid * 1024]);
    gll16(xf + g0 + 16, &sB[0][wid * 1024 + 512]);
    gll16(yf + g0,      &sB[0][4096 + wid * 1024]);
    gll16(yf + g0 + 16, &sB[0][4096 + wid * 1024 + 512]);
  }

#pragma unroll 1
  for (int pp = 0; pp < NP; ++pp) {
    const int cur = pp & 1;
    __syncthreads();
    if (pp + 1 < NP) {
      const size_t g0 = (size_t)(j0ch + (pp + 1) * 32 + srow) * DD + sk0;
      gll16(xf + g0,      &sB[cur ^ 1][wid * 1024]);
      gll16(xf + g0 + 16, &sB[cur ^ 1][wid * 1024 + 512]);
      gll16(yf + g0,      &sB[cur ^ 1][4096 + wid * 1024]);
      gll16(yf + g0 + 16, &sB[cur ^ 1][4096 + wid * 1024 + 512]);
    }

    f32x4 aS[2][2], aT[2][2];
#pragma unroll
    for (int at = 0; at < 2; ++at)
#pragma unroll
      for (int t = 0; t < 2; ++t) { aS[at][t] = {0.f,0.f,0.f,0.f}; aT[at][t] = {0.f,0.f,0.f,0.f}; }
#pragma unroll
    for (int s = 0; s < 4; ++s) {
#pragma unroll
      for (int t = 0; t < 2; ++t) {
        const int ro = (s * 128 + hi_l * 32 + t * 16 + l15) * 8;
        half8 vX = *reinterpret_cast<const half8*>(&sB[cur][ro]);
        half8 vY = *reinterpret_cast<const half8*>(&sB[cur][4096 + ro]);
        aS[0][t] = mfma16h(Ax[0][s], vX, aS[0][t]);
        aS[1][t] = mfma16h(Ax[1][s], vX, aS[1][t]);
        aT[0][t] = mfma16h(Ay[0][s], vY, aT[0][t]);
        aT[1][t] = mfma16h(Ay[1][s], vY, aT[1][t]);
      }
    }

#pragma unroll
    for (int t = 0; t < 2; ++t) {
      const int lj   = sJlab[pp * 32 + t * 16 + l15];
      const int jcol = j0ch + pp * 32 + t * 16 + l15;
#pragma unroll
      for (int at = 0; at < 2; ++at)
#pragma unroll
        for (int r = 0; r < 4; ++r) {
          float sim = aS[at][t][r], tsim = aT[at][t][r];
          bool same = (lj == labA[at][r]);
          float sc = same ? 0.25f : 0.125f;
          float s  = sim * sc;
          float ts = tsim * sc;
          zs[at][r] += __expf(s);
          float et = __expf(ts);
          zt[at][r] += et;
          wv[at][r] += et * (ts - s);
          if (same) {
            if (jcol != i0w + at * 16 + rbase + r) mp[at][r] = fminf(mp[at][r], sim);
          } else {
            mn[at][r] = fmaxf(mn[at][r], sim);
          }
        }
    }
  }

#pragma unroll
  for (int at = 0; at < 2; ++at)
#pragma unroll
    for (int r = 0; r < 4; ++r)
#pragma unroll
      for (int m = 1; m < 16; m <<= 1) {
        zs[at][r] += __shfl_xor(zs[at][r], m);
        mp[at][r] = fminf(mp[at][r], __shfl_xor(mp[at][r], m));
        mn[at][r] = fmaxf(mn[at][r], __shfl_xor(mn[at][r], m));
        zt[at][r] += __shfl_xor(zt[at][r], m);
        wv[at][r] += __shfl_xor(wv[at][r], m);
      }
  if (l15 == 0) {
#pragma unroll
    for (int at = 0; at < 2; ++at)
#pragma unroll
      for (int r = 0; r < 4; ++r) {
        const int i_r = i0w + at * 16 + rbase + r;
        zsP[ch * BB + i_r] = zs[at][r];
        mpP[ch * BB + i_r] = mp[at][r];
        mnP[ch * BB + i_r] = mn[at][r];
        ztP[ch * BB + i_r] = zt[at][r];
        wvP[ch * BB + i_r] = wv[at][r];
      }
  }
}

// ============ kG2: batch Gram -> ps/ns chunk partials (reduces mp/mn) ======
__global__ __launch_bounds__(TB, 3) void kG2(
    const unsigned short* __restrict__ xf,
    const int* __restrict__ labels,
    const float* __restrict__ mpP, const float* __restrict__ mnP,
    float* __restrict__ psP, float* __restrict__ nsP)
{
  __shared__ unsigned short sX[2][4096];   // 2 bufs x 8 KB
  __shared__ int sJlab[128];
  __shared__ float sMPr[128], sMNr[128];

  const int tid  = threadIdx.x;
  const int lane = tid & 63;
  const int wid  = tid >> 6;
  const int ag   = blockIdx.x & 31;
  const int ch   = blockIdx.x >> 5;
  const int i0w  = ag * 128 + wid * 32;
  const int l15  = lane & 15;
  const int hi_l = lane >> 4;
  const int rbase = hi_l * 4;
  const int koff  = hi_l * 8;
  const int j0ch  = ch * 128;
  const int srow  = lane & 31;
  const int sk0   = wid * 32 + (lane >> 5) * 8;

  { // prologue stage: panel 0 -> buf 0 (issue first; hides under reduce)
    const size_t g0 = (size_t)(j0ch + srow) * DD + sk0;
    gll16(xf + g0,      &sX[0][wid * 1024]);
    gll16(xf + g0 + 16, &sX[0][wid * 1024 + 512]);
  }

  if (tid < 128) {
    sJlab[tid] = labels[j0ch + tid];
    const int aidx = ag * 128 + tid;
    float a = INFINITY, b = -INFINITY;
#pragma unroll
    for (int c = 0; c < NCH; ++c) {
      a = fminf(a, mpP[c * BB + aidx]);
      b = fmaxf(b, mnP[c * BB + aidx]);
    }
    sMPr[tid] = a; sMNr[tid] = b;
  }

  half8 Ax[2][4];
#pragma unroll
  for (int at = 0; at < 2; ++at) {
    const size_t ab = (size_t)(i0w + at * 16 + l15) * DD + koff;
#pragma unroll
    for (int s = 0; s < 4; ++s)
      Ax[at][s] = *reinterpret_cast<const half8*>(xf + ab + s * 32);
  }
  int labA[2][4];
#pragma unroll
  for (int at = 0; at < 2; ++at)
#pragma unroll
    for (int r = 0; r < 4; ++r) labA[at][r] = labels[i0w + at * 16 + rbase + r];

  __syncthreads();         // sMPr/sMNr + sJlab visible (also drains buf0)
  float mpA[2][4], mnA[2][4];
#pragma unroll
  for (int at = 0; at < 2; ++at)
#pragma unroll
    for (int r = 0; r < 4; ++r) {
      const int al = wid * 32 + at * 16 + rbase + r;
      mpA[at][r] = sMPr[al];
      mnA[at][r] = sMNr[al];
    }

  float ps[2][4], ns[2][4];
#pragma unroll
  for (int at = 0; at < 2; ++at)
#pragma unroll
    for (int r = 0; r < 4; ++r) { ps[at][r] = 0.f; ns[at][r] = 0.f; }

#pragma unroll 1
  for (int pp = 0; pp < NP; ++pp) {
    const int cur = pp & 1;
    if (pp) __syncthreads();
    if (pp + 1 < NP) {
      const size_t g0 = (size_t)(j0ch + (pp + 1) * 32 + srow) * DD + sk0;
      gll16(xf + g0,      &sX[cur ^ 1][wid * 1024]);
      gll16(xf + g0 + 16, &sX[cur ^ 1][wid * 1024 + 512]);
    }

    f32x4 acc[2][2];
#pragma unroll
    for (int at = 0; at < 2; ++at)
#pragma unroll
      for (int t = 0; t < 2; ++t) acc[at][t] = {0.f, 0.f, 0.f, 0.f};
#pragma unroll
    for (int s = 0; s < 4; ++s) {
#pragma unroll
      for (int t = 0; t < 2; ++t) {
        const int ro = (s * 128 + hi_l * 32 + t * 16 + l15) * 8;
        half8 vB = *reinterpret_cast<const half8*>(&sX[cur][ro]);
        acc[0][t] = mfma16h(Ax[0][s], vB, acc[0][t]);
        acc[1][t] = mfma16h(Ax[1][s], vB, acc[1][t]);
      }
    }

#pragma unroll
    for (int t = 0; t < 2; ++t) {
      const int lj   = sJlab[pp * 32 + t * 16 + l15];
      const int jcol = j0ch + pp * 32 + t * 16 + l15;
#pragma unroll
      for (int at = 0; at < 2; ++at)
#pragma unroll
        for (int r = 0; r < 4; ++r) {
          float sim = acc[at][t][r];
          bool same = (lj == labA[at][r]);
          if (same) {
            if (jcol != i0w + at * 16 + rbase + r && (sim - MARGIN < mnA[at][r]))
              ps[at][r] += __expf(-POS_W * (sim - THRESH));
          } else {
            if (sim + MARGIN > mpA[at][r])
              ns[at][r] += __expf(NEG_W * (sim - THRESH));
          }
        }
    }
  }

#pragma unroll
  for (int at = 0; at < 2; ++at)
#pragma unroll
    for (int r = 0; r < 4; ++r)
#pragma unroll
      for (int m = 1; m < 16; m <<= 1) {
        ps[at][r] += __shfl_xor(ps[at][r], m);
        ns[at][r] += __shfl_xor(ns[at][r], m);
      }
  if (l15 == 0) {
#pragma unroll
    for (int at = 0; at < 2; ++at)
#pragma unroll
      for (int r = 0; r < 4; ++r) {
        const int i_r = i0w + at * 16 + rbase + r;
        psP[ch * BB + i_r] = ps[at][r];
        nsP[ch * BB + i_r] = ns[at][r];
      }
  }
}

// ============ kD: finalize; last block merges (deterministic) ==============
__global__ __launch_bounds__(512) void kD(
    const float* __restrict__ zsP, const float* __restrict__ ztP,
    const float* __restrict__ wvP, const float* __restrict__ psP,
    const float* __restrict__ nsP, const int* __restrict__ epoch,
    double* __restrict__ rkP, double* __restrict__ kdP, int* __restrict__ nvP,
    int* __restrict__ cnt, float* __restrict__ out)
{
  __shared__ double sR[8], sK[8];
  __shared__ int    sN[8];
  const int tid = threadIdx.x;
  const int lane = tid & 63;
  const int wid = tid >> 6;
  const int i = blockIdx.x * 512 + tid;

  float zs = 0.f, zt = 0.f, wv = 0.f, ps = 0.f, ns = 0.f;
#pragma unroll
  for (int c = 0; c < NCH; ++c) {
    zs += zsP[c * BB + i];
    zt += ztP[c * BB + i];
    wv += wvP[c * BB + i];
    ps += psP[c * BB + i];
    ns += nsP[c * BB + i];
  }
  double kd = (double)(wv / zt + __logf(zs) - __logf(zt));
  double rank = 0.0; int nv = 0;
  if (ps > 0.f && ns > 0.f) {
    rank = (double)(log1pf(ps) * 0.5f + log1pf(ns) * 0.025f);
    nv = 1;
  }
#pragma unroll
  for (int o = 32; o; o >>= 1) {
    rank += __shfl_xor(rank, o);
    kd   += __shfl_xor(kd, o);
    nv   += __shfl_xor(nv, o);
  }
  if (lane == 0) { sR[wid] = rank; sK[wid] = kd; sN[wid] = nv; }
  __syncthreads();
  if (tid == 0) {
    double R_ = 0.0, K_ = 0.0; int N_ = 0;
    for (int w = 0; w < 8; ++w) { R_ += sR[w]; K_ += sK[w]; N_ += sN[w]; }
    rkP[blockIdx.x] = R_;
    kdP[blockIdx.x] = K_;
    nvP[blockIdx.x] = N_;
    __threadfence();
    int old = atomicAdd(cnt, 1);
    if (old == 7) {
      __threadfence();
      double RT = 0.0, KT = 0.0; int NT = 0;
      for (int b = 0; b < 8; ++b) { RT += rkP[b]; KT += kdP[b]; NT += nvP[b]; }
      double loss_rank = RT / (double)(NT < 1 ? 1 : NT);
      double loss_kd   = KT / (double)BB;
      double wgt = (double)epoch[0] * 0.16;   // epoch/100 * ALPHA * TAU^2
      out[0] = (float)(loss_rank + wgt * loss_kd);
      out[1] = (float)loss_rank;
      out[2] = (float)loss_kd;
      *cnt = 0;   // reset for next replay
    }
  }
}

extern "C" void kernel_launch(void* const* d_in, const int* in_sizes, int n_in,
                              void* d_out, int out_size, void* d_ws, size_t ws_size,
                              hipStream_t stream)
{
  (void)in_sizes; (void)n_in; (void)out_size; (void)ws_size;
  const float* batch   = (const float*)d_in[0];
  const float* teacher = (const float*)d_in[1];
  const int*   labels  = (const int*)d_in[2];
  const int*   epoch   = (const int*)d_in[3];
  float* out = (float*)d_out;

  char* w = (char*)d_ws;
  const size_t MB = 1048576;
  unsigned short* xf = (unsigned short*)(w + 0 * MB);   // 1 MB each
  unsigned short* yf = (unsigned short*)(w + 1 * MB);
  const size_t PCH = (size_t)NCH * BB * sizeof(float);  // 512 KB
  float* zsP = (float*)(w + 2 * MB + 0 * PCH);
  float* mpP = (float*)(w + 2 * MB + 1 * PCH);
  float* mnP = (float*)(w + 2 * MB + 2 * PCH);
  float* ztP = (float*)(w + 2 * MB + 3 * PCH);
  float* wvP = (float*)(w + 2 * MB + 4 * PCH);
  float* psP = (float*)(w + 2 * MB + 5 * PCH);
  float* nsP = (float*)(w + 2 * MB + 6 * PCH);
  double* rkP = (double*)(w + 6 * MB);
  double* kdP = (double*)(w + 6 * MB + 256);
  int*    nvP = (int*)(w + 6 * MB + 512);
  int*    cnt = (int*)(w + 6 * MB + 640);

  k0<<<dim3(BB * DD / 4 / 256), dim3(256), 0, stream>>>(batch, teacher, xf, yf, cnt);
  kG1<<<dim3(32 * NCH), dim3(TB), 0, stream>>>(xf, yf, labels,
                                               zsP, mpP, mnP, ztP, wvP);
  kG2<<<dim3(32 * NCH), dim3(TB), 0, stream>>>(xf, labels, mpP, mnP, psP, nsP);
  kD<<<dim3(8), dim3(512), 0, stream>>>(zsP, ztP, wvP, psP, nsP, epoch,
                                        rkP, kdP, nvP, cnt, out);
}

// Round 17
// 65.088 us; speedup vs baseline: 2.6802x; 1.0678x over previous
//
#include <hip/hip_runtime.h>
#include <hip/hip_fp16.h>
#include <math.h>

#define BB  4096
#define DD  128
#define NCH 16             // j-chunks (256 j each)
#define NP  8              // panels per chunk (32 j each)
#define TB  256            // threads per block (4 waves)

typedef __attribute__((ext_vector_type(8))) _Float16 half8;
typedef __attribute__((ext_vector_type(4))) float f32x4;

constexpr float POS_W  = 2.0f;
constexpr float NEG_W  = 40.0f;
constexpr float MARGIN = 0.1f;
constexpr float THRESH = 0.5f;

__device__ __forceinline__ unsigned short f2h(float f) {
  __half h = __float2half(f);
  return __half_as_ushort(h);
}
__device__ __forceinline__ float h2f(unsigned short u) {
  _Float16 h;
  __builtin_memcpy(&h, &u, 2);
  return (float)h;
}
__device__ __forceinline__ f32x4 mfma16h(half8 a, half8 b, f32x4 c) {
  return __builtin_amdgcn_mfma_f32_16x16x32_f16(a, b, c, 0, 0, 0);
}
// async global->LDS, 16B per lane; lds dest = uniform base + lane*16
__device__ __forceinline__ void gll16(const void* g, void* l) {
  __builtin_amdgcn_global_load_lds(
      (const __attribute__((address_space(1))) void*)g,
      (__attribute__((address_space(3))) void*)l, 16, 0, 0);
}

// ============ k0: fp32 -> fp16 for batch & teacher (+ zero cnt) ============
__global__ __launch_bounds__(256) void k0(
    const float* __restrict__ b, const float* __restrict__ t,
    unsigned short* __restrict__ xf, unsigned short* __restrict__ yf,
    int* __restrict__ cnt)
{
  const int i = blockIdx.x * 256 + threadIdx.x;   // < BB*DD/4 = 131072
  if (i == 0) *cnt = 0;
  {
    float4 v = reinterpret_cast<const float4*>(b)[i];
    ushort4 h;
    h.x = f2h(v.x); h.y = f2h(v.y); h.z = f2h(v.z); h.w = f2h(v.w);
    reinterpret_cast<ushort4*>(xf)[i] = h;
  }
  {
    float4 v = reinterpret_cast<const float4*>(t)[i];
    ushort4 h;
    h.x = f2h(v.x); h.y = f2h(v.y); h.z = f2h(v.z); h.w = f2h(v.w);
    reinterpret_cast<ushort4*>(yf)[i] = h;
  }
}

// LDS panel layout (per array, 32-j panel, 8 KB = 512 slots of 16B):
//   slot = S*128 + H*32 + J  <-> row J, k=[S*32+H*8,+8)
// staging: wave wid covers S=wid; shot s2: dest slots wid*128 + s2*64 + lane
// fragment read (k-step s, j-tile t): slot = s*128 + hi_l*32 + t*16 + l15
//
// sim store (fragment-linear, fp16): ushort4 (4 r-values) at
//   simh4[blk*8192 + wid*2048 + ((pp*2+t)*2+at)*64 + lane]
// -> consecutive lanes = consecutive 8B: 512B/wave store, coalesced.

// ============ kG1: X+Y Grams -> zs/mp/mn/zt/wv partials + sim(fp16) ========
__global__ __launch_bounds__(TB, 2) void kG1(
    const unsigned short* __restrict__ xf, const unsigned short* __restrict__ yf,
    const int* __restrict__ labels,
    float* __restrict__ zsP, float* __restrict__ mpP, float* __restrict__ mnP,
    float* __restrict__ ztP, float* __restrict__ wvP,
    ushort4* __restrict__ simh4)
{
  __shared__ unsigned short sB[2][8192];   // 2 bufs x (X 8KB + Y 8KB) = 32 KB
  __shared__ int sJlab[256];

  const int tid  = threadIdx.x;
  const int lane = tid & 63;
  const int wid  = tid >> 6;
  const int ag   = blockIdx.x & 31;
  const int ch   = blockIdx.x >> 5;
  const int i0w  = ag * 128 + wid * 32;
  const int l15  = lane & 15;
  const int hi_l = lane >> 4;
  const int rbase = hi_l * 4;
  const int koff  = hi_l * 8;
  const int j0ch  = ch * 256;
  const int srow  = lane & 31;
  const int sk0   = wid * 32 + (lane >> 5) * 8;

  ushort4* sblk = simh4 + (size_t)blockIdx.x * 8192 + wid * 2048 + lane;

  sJlab[tid] = labels[j0ch + tid];

  half8 Ax[2][4], Ay[2][4];
#pragma unroll
  for (int at = 0; at < 2; ++at) {
    const size_t ab = (size_t)(i0w + at * 16 + l15) * DD + koff;
#pragma unroll
    for (int s = 0; s < 4; ++s) {
      Ax[at][s] = *reinterpret_cast<const half8*>(xf + ab + s * 32);
      Ay[at][s] = *reinterpret_cast<const half8*>(yf + ab + s * 32);
    }
  }
  int labA[2][4];
#pragma unroll
  for (int at = 0; at < 2; ++at)
#pragma unroll
    for (int r = 0; r < 4; ++r) labA[at][r] = labels[i0w + at * 16 + rbase + r];

  float zs[2][4], mp[2][4], mn[2][4], zt[2][4], wv[2][4];
#pragma unroll
  for (int at = 0; at < 2; ++at)
#pragma unroll
    for (int r = 0; r < 4; ++r) {
      zs[at][r] = 0.f; mp[at][r] = INFINITY; mn[at][r] = -INFINITY;
      zt[at][r] = 0.f; wv[at][r] = 0.f;
    }

  { // prologue stage: panel 0 -> buf 0 (X then Y, 2 shots each)
    const size_t g0 = (size_t)(j0ch + srow) * DD + sk0;
    gll16(xf + g0,      &sB[0][wid * 1024]);
    gll16(xf + g0 + 16, &sB[0][wid * 1024 + 512]);
    gll16(yf + g0,      &sB[0][4096 + wid * 1024]);
    gll16(yf + g0 + 16, &sB[0][4096 + wid * 1024 + 512]);
  }

#pragma unroll 1
  for (int pp = 0; pp < NP; ++pp) {
    const int cur = pp & 1;
    __syncthreads();
    if (pp + 1 < NP) {
      const size_t g0 = (size_t)(j0ch + (pp + 1) * 32 + srow) * DD + sk0;
      gll16(xf + g0,      &sB[cur ^ 1][wid * 1024]);
      gll16(xf + g0 + 16, &sB[cur ^ 1][wid * 1024 + 512]);
      gll16(yf + g0,      &sB[cur ^ 1][4096 + wid * 1024]);
      gll16(yf + g0 + 16, &sB[cur ^ 1][4096 + wid * 1024 + 512]);
    }

    f32x4 aS[2][2], aT[2][2];
#pragma unroll
    for (int at = 0; at < 2; ++at)
#pragma unroll
      for (int t = 0; t < 2; ++t) { aS[at][t] = {0.f,0.f,0.f,0.f}; aT[at][t] = {0.f,0.f,0.f,0.f}; }
#pragma unroll
    for (int s = 0; s < 4; ++s) {
#pragma unroll
      for (int t = 0; t < 2; ++t) {
        const int ro = (s * 128 + hi_l * 32 + t * 16 + l15) * 8;
        half8 vX = *reinterpret_cast<const half8*>(&sB[cur][ro]);
        half8 vY = *reinterpret_cast<const half8*>(&sB[cur][4096 + ro]);
        aS[0][t] = mfma16h(Ax[0][s], vX, aS[0][t]);
        aS[1][t] = mfma16h(Ax[1][s], vX, aS[1][t]);
        aT[0][t] = mfma16h(Ay[0][s], vY, aT[0][t]);
        aT[1][t] = mfma16h(Ay[1][s], vY, aT[1][t]);
      }
    }

    // store sims (fp16, fragment-linear, coalesced 512B/wave)
#pragma unroll
    for (int t = 0; t < 2; ++t)
#pragma unroll
      for (int at = 0; at < 2; ++at) {
        ushort4 h4;
        h4.x = f2h(aS[at][t][0]); h4.y = f2h(aS[at][t][1]);
        h4.z = f2h(aS[at][t][2]); h4.w = f2h(aS[at][t][3]);
        sblk[((pp * 2 + t) * 2 + at) * 64] = h4;
      }

#pragma unroll
    for (int t = 0; t < 2; ++t) {
      const int lj   = sJlab[pp * 32 + t * 16 + l15];
      const int jcol = j0ch + pp * 32 + t * 16 + l15;
#pragma unroll
      for (int at = 0; at < 2; ++at)
#pragma unroll
        for (int r = 0; r < 4; ++r) {
          float sim = aS[at][t][r], tsim = aT[at][t][r];
          bool same = (lj == labA[at][r]);
          float sc = same ? 0.25f : 0.125f;
          float s  = sim * sc;
          float ts = tsim * sc;
          zs[at][r] += __expf(s);
          float et = __expf(ts);
          zt[at][r] += et;
          wv[at][r] += et * (ts - s);
          if (same) {
            if (jcol != i0w + at * 16 + rbase + r) mp[at][r] = fminf(mp[at][r], sim);
          } else {
            mn[at][r] = fmaxf(mn[at][r], sim);
          }
        }
    }
  }

#pragma unroll
  for (int at = 0; at < 2; ++at)
#pragma unroll
    for (int r = 0; r < 4; ++r)
#pragma unroll
      for (int m = 1; m < 16; m <<= 1) {
        zs[at][r] += __shfl_xor(zs[at][r], m);
        mp[at][r] = fminf(mp[at][r], __shfl_xor(mp[at][r], m));
        mn[at][r] = fmaxf(mn[at][r], __shfl_xor(mn[at][r], m));
        zt[at][r] += __shfl_xor(zt[at][r], m);
        wv[at][r] += __shfl_xor(wv[at][r], m);
      }
  if (l15 == 0) {
#pragma unroll
    for (int at = 0; at < 2; ++at)
#pragma unroll
      for (int r = 0; r < 4; ++r) {
        const int i_r = i0w + at * 16 + rbase + r;
        zsP[ch * BB + i_r] = zs[at][r];
        mpP[ch * BB + i_r] = mp[at][r];
        mnP[ch * BB + i_r] = mn[at][r];
        ztP[ch * BB + i_r] = zt[at][r];
        wvP[ch * BB + i_r] = wv[at][r];
      }
  }
}

// ============ kG2: stream stored sims -> ps/ns partials (no MFMA) ==========
__global__ __launch_bounds__(TB, 4) void kG2(
    const ushort4* __restrict__ simh4,
    const int* __restrict__ labels,
    const float* __restrict__ mpP, const float* __restrict__ mnP,
    float* __restrict__ psP, float* __restrict__ nsP)
{
  __shared__ int sJlab[256];
  __shared__ float sMPr[128], sMNr[128];

  const int tid  = threadIdx.x;
  const int lane = tid & 63;
  const int wid  = tid >> 6;
  const int ag   = blockIdx.x & 31;
  const int ch   = blockIdx.x >> 5;
  const int i0w  = ag * 128 + wid * 32;
  const int l15  = lane & 15;
  const int hi_l = lane >> 4;
  const int rbase = hi_l * 4;
  const int j0ch  = ch * 256;

  sJlab[tid] = labels[j0ch + tid];
  if (tid < 128) {          // block-wide reduce of the 16 mp/mn chunk partials
    const int aidx = ag * 128 + tid;
    float a = INFINITY, b = -INFINITY;
#pragma unroll
    for (int c = 0; c < NCH; ++c) {
      a = fminf(a, mpP[c * BB + aidx]);
      b = fmaxf(b, mnP[c * BB + aidx]);
    }
    sMPr[tid] = a; sMNr[tid] = b;
  }

  int labA[2][4];
#pragma unroll
  for (int at = 0; at < 2; ++at)
#pragma unroll
    for (int r = 0; r < 4; ++r) labA[at][r] = labels[i0w + at * 16 + rbase + r];

  __syncthreads();
  float mpA[2][4], mnA[2][4];
#pragma unroll
  for (int at = 0; at < 2; ++at)
#pragma unroll
    for (int r = 0; r < 4; ++r) {
      const int al = wid * 32 + at * 16 + rbase + r;
      mpA[at][r] = sMPr[al];
      mnA[at][r] = sMNr[al];
    }

  float ps[2][4], ns[2][4];
#pragma unroll
  for (int at = 0; at < 2; ++at)
#pragma unroll
    for (int r = 0; r < 4; ++r) { ps[at][r] = 0.f; ns[at][r] = 0.f; }

  const ushort4* sblk = simh4 + (size_t)blockIdx.x * 8192 + wid * 2048 + lane;

#pragma unroll 2
  for (int pp = 0; pp < NP; ++pp) {
#pragma unroll
    for (int t = 0; t < 2; ++t) {
      const int lj   = sJlab[pp * 32 + t * 16 + l15];
      const int jcol = j0ch + pp * 32 + t * 16 + l15;
#pragma unroll
      for (int at = 0; at < 2; ++at) {
        ushort4 v = sblk[((pp * 2 + t) * 2 + at) * 64];
        float sv[4] = { h2f(v.x), h2f(v.y), h2f(v.z), h2f(v.w) };
#pragma unroll
        for (int r = 0; r < 4; ++r) {
          float sim = sv[r];
          bool same = (lj == labA[at][r]);
          if (same) {
            if (jcol != i0w + at * 16 + rbase + r && (sim - MARGIN < mnA[at][r]))
              ps[at][r] += __expf(-POS_W * (sim - THRESH));
          } else {
            if (sim + MARGIN > mpA[at][r])
              ns[at][r] += __expf(NEG_W * (sim - THRESH));
          }
        }
      }
    }
  }

#pragma unroll
  for (int at = 0; at < 2; ++at)
#pragma unroll
    for (int r = 0; r < 4; ++r)
#pragma unroll
      for (int m = 1; m < 16; m <<= 1) {
        ps[at][r] += __shfl_xor(ps[at][r], m);
        ns[at][r] += __shfl_xor(ns[at][r], m);
      }
  if (l15 == 0) {
#pragma unroll
    for (int at = 0; at < 2; ++at)
#pragma unroll
      for (int r = 0; r < 4; ++r) {
        const int i_r = i0w + at * 16 + rbase + r;
        psP[ch * BB + i_r] = ps[at][r];
        nsP[ch * BB + i_r] = ns[at][r];
      }
  }
}

// ============ kD: finalize; last block merges (deterministic) ==============
__global__ __launch_bounds__(512) void kD(
    const float* __restrict__ zsP, const float* __restrict__ ztP,
    const float* __restrict__ wvP, const float* __restrict__ psP,
    const float* __restrict__ nsP, const int* __restrict__ epoch,
    double* __restrict__ rkP, double* __restrict__ kdP, int* __restrict__ nvP,
    int* __restrict__ cnt, float* __restrict__ out)
{
  __shared__ double sR[8], sK[8];
  __shared__ int    sN[8];
  const int tid = threadIdx.x;
  const int lane = tid & 63;
  const int wid = tid >> 6;
  const int i = blockIdx.x * 512 + tid;

  float zs = 0.f, zt = 0.f, wv = 0.f, ps = 0.f, ns = 0.f;
#pragma unroll
  for (int c = 0; c < NCH; ++c) {
    zs += zsP[c * BB + i];
    zt += ztP[c * BB + i];
    wv += wvP[c * BB + i];
    ps += psP[c * BB + i];
    ns += nsP[c * BB + i];
  }
  double kd = (double)(wv / zt + __logf(zs) - __logf(zt));
  double rank = 0.0; int nv = 0;
  if (ps > 0.f && ns > 0.f) {
    rank = (double)(log1pf(ps) * 0.5f + log1pf(ns) * 0.025f);
    nv = 1;
  }
#pragma unroll
  for (int o = 32; o; o >>= 1) {
    rank += __shfl_xor(rank, o);
    kd   += __shfl_xor(kd, o);
    nv   += __shfl_xor(nv, o);
  }
  if (lane == 0) { sR[wid] = rank; sK[wid] = kd; sN[wid] = nv; }
  __syncthreads();
  if (tid == 0) {
    double R_ = 0.0, K_ = 0.0; int N_ = 0;
    for (int w = 0; w < 8; ++w) { R_ += sR[w]; K_ += sK[w]; N_ += sN[w]; }
    rkP[blockIdx.x] = R_;
    kdP[blockIdx.x] = K_;
    nvP[blockIdx.x] = N_;
    __threadfence();
    int old = atomicAdd(cnt, 1);
    if (old == 7) {
      __threadfence();
      double RT = 0.0, KT = 0.0; int NT = 0;
      for (int b = 0; b < 8; ++b) { RT += rkP[b]; KT += kdP[b]; NT += nvP[b]; }
      double loss_rank = RT / (double)(NT < 1 ? 1 : NT);
      double loss_kd   = KT / (double)BB;
      double wgt = (double)epoch[0] * 0.16;   // epoch/100 * ALPHA * TAU^2
      out[0] = (float)(loss_rank + wgt * loss_kd);
      out[1] = (float)loss_rank;
      out[2] = (float)loss_kd;
      *cnt = 0;   // reset for next replay
    }
  }
}

extern "C" void kernel_launch(void* const* d_in, const int* in_sizes, int n_in,
                              void* d_out, int out_size, void* d_ws, size_t ws_size,
                              hipStream_t stream)
{
  (void)in_sizes; (void)n_in; (void)out_size; (void)ws_size;
  const float* batch   = (const float*)d_in[0];
  const float* teacher = (const float*)d_in[1];
  const int*   labels  = (const int*)d_in[2];
  const int*   epoch   = (const int*)d_in[3];
  float* out = (float*)d_out;

  char* w = (char*)d_ws;
  const size_t MB = 1048576;
  unsigned short* xf = (unsigned short*)(w + 0 * MB);   // 1 MB each
  unsigned short* yf = (unsigned short*)(w + 1 * MB);
  const size_t PCH = (size_t)NCH * BB * sizeof(float);  // 256 KB
  float* zsP = (float*)(w + 2 * MB + 0 * PCH);
  float* mpP = (float*)(w + 2 * MB + 1 * PCH);
  float* mnP = (float*)(w + 2 * MB + 2 * PCH);
  float* ztP = (float*)(w + 2 * MB + 3 * PCH);
  float* wvP = (float*)(w + 2 * MB + 4 * PCH);
  float* psP = (float*)(w + 2 * MB + 5 * PCH);
  float* nsP = (float*)(w + 2 * MB + 6 * PCH);
  double* rkP = (double*)(w + 4 * MB);
  double* kdP = (double*)(w + 4 * MB + 256);
  int*    nvP = (int*)(w + 4 * MB + 512);
  int*    cnt = (int*)(w + 4 * MB + 640);
  ushort4* simh4 = (ushort4*)(w + 8 * MB);              // 33.5 MB

  k0<<<dim3(BB * DD / 4 / 256), dim3(256), 0, stream>>>(batch, teacher, xf, yf, cnt);
  kG1<<<dim3(32 * NCH), dim3(TB), 0, stream>>>(xf, yf, labels,
                                               zsP, mpP, mnP, ztP, wvP, simh4);
  kG2<<<dim3(32 * NCH), dim3(TB), 0, stream>>>(simh4, labels, mpP, mnP, psP, nsP);
  kD<<<dim3(8), dim3(512), 0, stream>>>(zsP, ztP, wvP, psP, nsP, epoch,
                                        rkP, kdP, nvP, cnt, out);
}

// Round 18
// 59.034 us; speedup vs baseline: 2.9550x; 1.1026x over previous
//
#include <hip/hip_runtime.h>
#include <hip/hip_fp16.h>
#include <math.h>

#define BB  4096
#define DD  128
#define NCH 16             // j-chunks (256 j each)
#define NP  8              // panels per chunk (32 j each)
#define TB  256            // threads per block (4 waves)

typedef __attribute__((ext_vector_type(8))) _Float16 half8;
typedef __attribute__((ext_vector_type(4))) float f32x4;

constexpr float POS_W  = 2.0f;
constexpr float NEG_W  = 40.0f;
constexpr float MARGIN = 0.1f;
constexpr float THRESH = 0.5f;

__device__ __forceinline__ unsigned short f2h(float f) {
  __half h = __float2half(f);
  return __half_as_ushort(h);
}
__device__ __forceinline__ f32x4 mfma16h(half8 a, half8 b, f32x4 c) {
  return __builtin_amdgcn_mfma_f32_16x16x32_f16(a, b, c, 0, 0, 0);
}
// async global->LDS, 16B per lane; lds dest = uniform base + lane*16
__device__ __forceinline__ void gll16(const void* g, void* l) {
  __builtin_amdgcn_global_load_lds(
      (const __attribute__((address_space(1))) void*)g,
      (__attribute__((address_space(3))) void*)l, 16, 0, 0);
}

// ============ k0: fp32 -> fp16 for batch & teacher (+ zero cnt) ============
__global__ __launch_bounds__(256) void k0(
    const float* __restrict__ b, const float* __restrict__ t,
    unsigned short* __restrict__ xf, unsigned short* __restrict__ yf,
    int* __restrict__ cnt)
{
  const int i = blockIdx.x * 256 + threadIdx.x;   // < BB*DD/4 = 131072
  if (i == 0) *cnt = 0;
  {
    float4 v = reinterpret_cast<const float4*>(b)[i];
    ushort4 h;
    h.x = f2h(v.x); h.y = f2h(v.y); h.z = f2h(v.z); h.w = f2h(v.w);
    reinterpret_cast<ushort4*>(xf)[i] = h;
  }
  {
    float4 v = reinterpret_cast<const float4*>(t)[i];
    ushort4 h;
    h.x = f2h(v.x); h.y = f2h(v.y); h.z = f2h(v.z); h.w = f2h(v.w);
    reinterpret_cast<ushort4*>(yf)[i] = h;
  }
}

// LDS panel layout (per array, 32-j panel, 8 KB = 512 slots of 16B):
//   slot = S*128 + H*32 + J   (S=k-step, H=k-sub, J=j)  <-> row J, k=[S*32+H*8,+8)
// staging: wave wid covers S=wid; shot s2: dest slots wid*128 + s2*64 + lane
//   source row = j0p + (lane&31), k = wid*32 + (s2*2 + (lane>>5))*8
// fragment read (k-step s, j-tile t): slot = s*128 + hi_l*32 + t*16 + l15

// ============ kG1: batch+teacher Grams -> zs/mp/mn/zt/wv chunk partials ====
__global__ __launch_bounds__(TB, 2) void kG1(
    const unsigned short* __restrict__ xf, const unsigned short* __restrict__ yf,
    const int* __restrict__ labels,
    float* __restrict__ zsP, float* __restrict__ mpP, float* __restrict__ mnP,
    float* __restrict__ ztP, float* __restrict__ wvP)
{
  __shared__ unsigned short sB[2][8192];   // 2 bufs x (X 8KB + Y 8KB) = 32 KB
  __shared__ int sJlab[256];

  const int tid  = threadIdx.x;
  const int lane = tid & 63;
  const int wid  = tid >> 6;
  const int ag   = blockIdx.x & 31;
  const int ch   = blockIdx.x >> 5;
  const int i0w  = ag * 128 + wid * 32;
  const int l15  = lane & 15;
  const int hi_l = lane >> 4;
  const int rbase = hi_l * 4;
  const int koff  = hi_l * 8;
  const int j0ch  = ch * 256;
  const int srow  = lane & 31;
  const int sk0   = wid * 32 + (lane >> 5) * 8;

  sJlab[tid] = labels[j0ch + tid];

  half8 Ax[2][4], Ay[2][4];
#pragma unroll
  for (int at = 0; at < 2; ++at) {
    const size_t ab = (size_t)(i0w + at * 16 + l15) * DD + koff;
#pragma unroll
    for (int s = 0; s < 4; ++s) {
      Ax[at][s] = *reinterpret_cast<const half8*>(xf + ab + s * 32);
      Ay[at][s] = *reinterpret_cast<const half8*>(yf + ab + s * 32);
    }
  }
  int labA[2][4];
#pragma unroll
  for (int at = 0; at < 2; ++at)
#pragma unroll
    for (int r = 0; r < 4; ++r) labA[at][r] = labels[i0w + at * 16 + rbase + r];

  float zs[2][4], mp[2][4], mn[2][4], zt[2][4], wv[2][4];
#pragma unroll
  for (int at = 0; at < 2; ++at)
#pragma unroll
    for (int r = 0; r < 4; ++r) {
      zs[at][r] = 0.f; mp[at][r] = INFINITY; mn[at][r] = -INFINITY;
      zt[at][r] = 0.f; wv[at][r] = 0.f;
    }

  { // prologue stage: panel 0 -> buf 0 (X then Y, 2 shots each)
    const size_t g0 = (size_t)(j0ch + srow) * DD + sk0;
    gll16(xf + g0,      &sB[0][wid * 1024]);
    gll16(xf + g0 + 16, &sB[0][wid * 1024 + 512]);
    gll16(yf + g0,      &sB[0][4096 + wid * 1024]);
    gll16(yf + g0 + 16, &sB[0][4096 + wid * 1024 + 512]);
  }

#pragma unroll 1
  for (int pp = 0; pp < NP; ++pp) {
    const int cur = pp & 1;
    __syncthreads();
    if (pp + 1 < NP) {
      const size_t g0 = (size_t)(j0ch + (pp + 1) * 32 + srow) * DD + sk0;
      gll16(xf + g0,      &sB[cur ^ 1][wid * 1024]);
      gll16(xf + g0 + 16, &sB[cur ^ 1][wid * 1024 + 512]);
      gll16(yf + g0,      &sB[cur ^ 1][4096 + wid * 1024]);
      gll16(yf + g0 + 16, &sB[cur ^ 1][4096 + wid * 1024 + 512]);
    }

    f32x4 aS[2][2], aT[2][2];
#pragma unroll
    for (int at = 0; at < 2; ++at)
#pragma unroll
      for (int t = 0; t < 2; ++t) { aS[at][t] = {0.f,0.f,0.f,0.f}; aT[at][t] = {0.f,0.f,0.f,0.f}; }
#pragma unroll
    for (int s = 0; s < 4; ++s) {
#pragma unroll
      for (int t = 0; t < 2; ++t) {
        const int ro = (s * 128 + hi_l * 32 + t * 16 + l15) * 8;
        half8 vX = *reinterpret_cast<const half8*>(&sB[cur][ro]);
        half8 vY = *reinterpret_cast<const half8*>(&sB[cur][4096 + ro]);
        aS[0][t] = mfma16h(Ax[0][s], vX, aS[0][t]);
        aS[1][t] = mfma16h(Ax[1][s], vX, aS[1][t]);
        aT[0][t] = mfma16h(Ay[0][s], vY, aT[0][t]);
        aT[1][t] = mfma16h(Ay[1][s], vY, aT[1][t]);
      }
    }

#pragma unroll
    for (int t = 0; t < 2; ++t) {
      const int lj   = sJlab[pp * 32 + t * 16 + l15];
      const int jcol = j0ch + pp * 32 + t * 16 + l15;
#pragma unroll
      for (int at = 0; at < 2; ++at)
#pragma unroll
        for (int r = 0; r < 4; ++r) {
          float sim = aS[at][t][r], tsim = aT[at][t][r];
          bool same = (lj == labA[at][r]);
          float sc = same ? 0.25f : 0.125f;
          float s  = sim * sc;
          float ts = tsim * sc;
          zs[at][r] += __expf(s);
          float et = __expf(ts);
          zt[at][r] += et;
          wv[at][r] += et * (ts - s);
          if (same) {
            if (jcol != i0w + at * 16 + rbase + r) mp[at][r] = fminf(mp[at][r], sim);
          } else {
            mn[at][r] = fmaxf(mn[at][r], sim);
          }
        }
    }
  }

#pragma unroll
  for (int at = 0; at < 2; ++at)
#pragma unroll
    for (int r = 0; r < 4; ++r)
#pragma unroll
      for (int m = 1; m < 16; m <<= 1) {
        zs[at][r] += __shfl_xor(zs[at][r], m);
        mp[at][r] = fminf(mp[at][r], __shfl_xor(mp[at][r], m));
        mn[at][r] = fmaxf(mn[at][r], __shfl_xor(mn[at][r], m));
        zt[at][r] += __shfl_xor(zt[at][r], m);
        wv[at][r] += __shfl_xor(wv[at][r], m);
      }
  if (l15 == 0) {
#pragma unroll
    for (int at = 0; at < 2; ++at)
#pragma unroll
      for (int r = 0; r < 4; ++r) {
        const int i_r = i0w + at * 16 + rbase + r;
        zsP[ch * BB + i_r] = zs[at][r];
        mpP[ch * BB + i_r] = mp[at][r];
        mnP[ch * BB + i_r] = mn[at][r];
        ztP[ch * BB + i_r] = zt[at][r];
        wvP[ch * BB + i_r] = wv[at][r];
      }
  }
}

// ============ kG2: batch Gram -> ps/ns chunk partials (reduces mp/mn) ======
__global__ __launch_bounds__(TB, 3) void kG2(
    const unsigned short* __restrict__ xf,
    const int* __restrict__ labels,
    const float* __restrict__ mpP, const float* __restrict__ mnP,
    float* __restrict__ psP, float* __restrict__ nsP)
{
  __shared__ unsigned short sX[2][4096];   // 2 bufs x 8 KB
  __shared__ int sJlab[256];
  __shared__ float sMPr[128], sMNr[128];

  const int tid  = threadIdx.x;
  const int lane = tid & 63;
  const int wid  = tid >> 6;
  const int ag   = blockIdx.x & 31;
  const int ch   = blockIdx.x >> 5;
  const int i0w  = ag * 128 + wid * 32;
  const int l15  = lane & 15;
  const int hi_l = lane >> 4;
  const int rbase = hi_l * 4;
  const int koff  = hi_l * 8;
  const int j0ch  = ch * 256;
  const int srow  = lane & 31;
  const int sk0   = wid * 32 + (lane >> 5) * 8;

  { // prologue stage: panel 0 -> buf 0 (issue first; hides under reduce)
    const size_t g0 = (size_t)(j0ch + srow) * DD + sk0;
    gll16(xf + g0,      &sX[0][wid * 1024]);
    gll16(xf + g0 + 16, &sX[0][wid * 1024 + 512]);
  }

  sJlab[tid] = labels[j0ch + tid];
  if (tid < 128) {          // block-wide reduce of the 16 chunk partials
    const int aidx = ag * 128 + tid;
    float a = INFINITY, b = -INFINITY;
#pragma unroll
    for (int c = 0; c < NCH; ++c) {
      a = fminf(a, mpP[c * BB + aidx]);
      b = fmaxf(b, mnP[c * BB + aidx]);
    }
    sMPr[tid] = a; sMNr[tid] = b;
  }

  half8 Ax[2][4];
#pragma unroll
  for (int at = 0; at < 2; ++at) {
    const size_t ab = (size_t)(i0w + at * 16 + l15) * DD + koff;
#pragma unroll
    for (int s = 0; s < 4; ++s)
      Ax[at][s] = *reinterpret_cast<const half8*>(xf + ab + s * 32);
  }
  int labA[2][4];
#pragma unroll
  for (int at = 0; at < 2; ++at)
#pragma unroll
    for (int r = 0; r < 4; ++r) labA[at][r] = labels[i0w + at * 16 + rbase + r];

  __syncthreads();         // sMPr/sMNr + sJlab visible (also drains buf0)
  float mpA[2][4], mnA[2][4];
#pragma unroll
  for (int at = 0; at < 2; ++at)
#pragma unroll
    for (int r = 0; r < 4; ++r) {
      const int al = wid * 32 + at * 16 + rbase + r;
      mpA[at][r] = sMPr[al];
      mnA[at][r] = sMNr[al];
    }

  float ps[2][4], ns[2][4];
#pragma unroll
  for (int at = 0; at < 2; ++at)
#pragma unroll
    for (int r = 0; r < 4; ++r) { ps[at][r] = 0.f; ns[at][r] = 0.f; }

#pragma unroll 1
  for (int pp = 0; pp < NP; ++pp) {
    const int cur = pp & 1;
    if (pp) __syncthreads();
    if (pp + 1 < NP) {
      const size_t g0 = (size_t)(j0ch + (pp + 1) * 32 + srow) * DD + sk0;
      gll16(xf + g0,      &sX[cur ^ 1][wid * 1024]);
      gll16(xf + g0 + 16, &sX[cur ^ 1][wid * 1024 + 512]);
    }

    f32x4 acc[2][2];
#pragma unroll
    for (int at = 0; at < 2; ++at)
#pragma unroll
      for (int t = 0; t < 2; ++t) acc[at][t] = {0.f, 0.f, 0.f, 0.f};
#pragma unroll
    for (int s = 0; s < 4; ++s) {
#pragma unroll
      for (int t = 0; t < 2; ++t) {
        const int ro = (s * 128 + hi_l * 32 + t * 16 + l15) * 8;
        half8 vB = *reinterpret_cast<const half8*>(&sX[cur][ro]);
        acc[0][t] = mfma16h(Ax[0][s], vB, acc[0][t]);
        acc[1][t] = mfma16h(Ax[1][s], vB, acc[1][t]);
      }
    }

#pragma unroll
    for (int t = 0; t < 2; ++t) {
      const int lj   = sJlab[pp * 32 + t * 16 + l15];
      const int jcol = j0ch + pp * 32 + t * 16 + l15;
#pragma unroll
      for (int at = 0; at < 2; ++at)
#pragma unroll
        for (int r = 0; r < 4; ++r) {
          float sim = acc[at][t][r];
          bool same = (lj == labA[at][r]);
          if (same) {
            if (jcol != i0w + at * 16 + rbase + r && (sim - MARGIN < mnA[at][r]))
              ps[at][r] += __expf(-POS_W * (sim - THRESH));
          } else {
            if (sim + MARGIN > mpA[at][r])
              ns[at][r] += __expf(NEG_W * (sim - THRESH));
          }
        }
    }
  }

#pragma unroll
  for (int at = 0; at < 2; ++at)
#pragma unroll
    for (int r = 0; r < 4; ++r)
#pragma unroll
      for (int m = 1; m < 16; m <<= 1) {
        ps[at][r] += __shfl_xor(ps[at][r], m);
        ns[at][r] += __shfl_xor(ns[at][r], m);
      }
  if (l15 == 0) {
#pragma unroll
    for (int at = 0; at < 2; ++at)
#pragma unroll
      for (int r = 0; r < 4; ++r) {
        const int i_r = i0w + at * 16 + rbase + r;
        psP[ch * BB + i_r] = ps[at][r];
        nsP[ch * BB + i_r] = ns[at][r];
      }
  }
}

// ============ kD: finalize; last block merges (deterministic) ==============
__global__ __launch_bounds__(512) void kD(
    const float* __restrict__ zsP, const float* __restrict__ ztP,
    const float* __restrict__ wvP, const float* __restrict__ psP,
    const float* __restrict__ nsP, const int* __restrict__ epoch,
    double* __restrict__ rkP, double* __restrict__ kdP, int* __restrict__ nvP,
    int* __restrict__ cnt, float* __restrict__ out)
{
  __shared__ double sR[8], sK[8];
  __shared__ int    sN[8];
  const int tid = threadIdx.x;
  const int lane = tid & 63;
  const int wid = tid >> 6;
  const int i = blockIdx.x * 512 + tid;

  float zs = 0.f, zt = 0.f, wv = 0.f, ps = 0.f, ns = 0.f;
#pragma unroll
  for (int c = 0; c < NCH; ++c) {
    zs += zsP[c * BB + i];
    zt += ztP[c * BB + i];
    wv += wvP[c * BB + i];
    ps += psP[c * BB + i];
    ns += nsP[c * BB + i];
  }
  double kd = (double)(wv / zt + __logf(zs) - __logf(zt));
  double rank = 0.0; int nv = 0;
  if (ps > 0.f && ns > 0.f) {
    rank = (double)(log1pf(ps) * 0.5f + log1pf(ns) * 0.025f);
    nv = 1;
  }
#pragma unroll
  for (int o = 32; o; o >>= 1) {
    rank += __shfl_xor(rank, o);
    kd   += __shfl_xor(kd, o);
    nv   += __shfl_xor(nv, o);
  }
  if (lane == 0) { sR[wid] = rank; sK[wid] = kd; sN[wid] = nv; }
  __syncthreads();
  if (tid == 0) {
    double R_ = 0.0, K_ = 0.0; int N_ = 0;
    for (int w = 0; w < 8; ++w) { R_ += sR[w]; K_ += sK[w]; N_ += sN[w]; }
    rkP[blockIdx.x] = R_;
    kdP[blockIdx.x] = K_;
    nvP[blockIdx.x] = N_;
    __threadfence();
    int old = atomicAdd(cnt, 1);
    if (old == 7) {
      __threadfence();
      double RT = 0.0, KT = 0.0; int NT = 0;
      for (int b = 0; b < 8; ++b) { RT += rkP[b]; KT += kdP[b]; NT += nvP[b]; }
      double loss_rank = RT / (double)(NT < 1 ? 1 : NT);
      double loss_kd   = KT / (double)BB;
      double wgt = (double)epoch[0] * 0.16;   // epoch/100 * ALPHA * TAU^2
      out[0] = (float)(loss_rank + wgt * loss_kd);
      out[1] = (float)loss_rank;
      out[2] = (float)loss_kd;
      *cnt = 0;   // reset for next replay
    }
  }
}

extern "C" void kernel_launch(void* const* d_in, const int* in_sizes, int n_in,
                              void* d_out, int out_size, void* d_ws, size_t ws_size,
                              hipStream_t stream)
{
  (void)in_sizes; (void)n_in; (void)out_size; (void)ws_size;
  const float* batch   = (const float*)d_in[0];
  const float* teacher = (const float*)d_in[1];
  const int*   labels  = (const int*)d_in[2];
  const int*   epoch   = (const int*)d_in[3];
  float* out = (float*)d_out;

  char* w = (char*)d_ws;
  const size_t MB = 1048576;
  unsigned short* xf = (unsigned short*)(w + 0 * MB);   // 1 MB each
  unsigned short* yf = (unsigned short*)(w + 1 * MB);
  const size_t PCH = (size_t)NCH * BB * sizeof(float);  // 256 KB
  float* zsP = (float*)(w + 2 * MB + 0 * PCH);
  float* mpP = (float*)(w + 2 * MB + 1 * PCH);
  float* mnP = (float*)(w + 2 * MB + 2 * PCH);
  float* ztP = (float*)(w + 2 * MB + 3 * PCH);
  float* wvP = (float*)(w + 2 * MB + 4 * PCH);
  float* psP = (float*)(w + 2 * MB + 5 * PCH);
  float* nsP = (float*)(w + 2 * MB + 6 * PCH);
  double* rkP = (double*)(w + 4 * MB);
  double* kdP = (double*)(w + 4 * MB + 256);
  int*    nvP = (int*)(w + 4 * MB + 512);
  int*    cnt = (int*)(w + 4 * MB + 640);

  k0<<<dim3(BB * DD / 4 / 256), dim3(256), 0, stream>>>(batch, teacher, xf, yf, cnt);
  kG1<<<dim3(32 * NCH), dim3(TB), 0, stream>>>(xf, yf, labels,
                                               zsP, mpP, mnP, ztP, wvP);
  kG2<<<dim3(32 * NCH), dim3(TB), 0, stream>>>(xf, labels, mpP, mnP, psP, nsP);
  kD<<<dim3(8), dim3(512), 0, stream>>>(zsP, ztP, wvP, psP, nsP, epoch,
                                        rkP, kdP, nvP, cnt, out);
}